// Round 3
// baseline (304.951 us; speedup 1.0000x reference)
//
#include <hip/hip_runtime.h>
#include <math.h>

// ToneStack: 3 cascaded shelf biquads over x[64, 480000] fp32.
//
// R7: back to R5's memory structure (its 92us beat R6's DMA-load variant:
//   R6's 71KB LDS halved occupancy and we are VALU/latency-bound, not
//   BW-bound -- VALUBusy*dur was invariant 43-49us across R4-R6).
//   Two changes on the issue/residency side:
//   (1) single-cohort residency: HISTC=MTERM=21 (horizon 1344 samples;
//       slowest pole r=0.9907/sample -> per-chunk decay 0.55, truncation
//       err ~1e-4 << 0.03125 floor) -> OUTC=235 -> 32 blocks/row ->
//       NBLK=2048 = exactly 8 blocks/CU; __launch_bounds__(256,8)
//       (VGPR cap 64 -- R5 compiled to 64 naturally).
//   (2) pass2 replaced by superposition combine: pass1 writes zero-state
//       outputs y0 in place (still yields d); final y[n] = y0[n] +
//       cn[n].t6 where cn[n] = C*A^n (6 floats/sample, stride-8 in LDS,
//       simulated once per block by 6 lanes of wave 1, overlapped with
//       Horner). 6 fma + 2 broadcast LDS reads per sample vs 15 VALU.
//   Store path unchanged from R5 (wave-contiguous 1KB stores via LDS
//   transpose staging; WRITE amp fix that took 137->92us).

constexpr int T_LEN  = 480000;
constexpr int B_ROWS = 64;
constexpr int CHUNK  = 64;
constexpr int LOG2C  = 6;                     // A^64 = 6 squarings
constexpr int KCH    = T_LEN / CHUNK;         // 7500 chunks per row
constexpr int NT     = 256;                   // threads per block
constexpr int HISTC  = 21;                    // history chunks (1344 samples)
constexpr int MTERM  = 21;                    // Horner terms (= horizon)
constexpr int OUTC   = NT - HISTC;            // 235 output chunks per block
constexpr int BLKROW = (KCH + OUTC - 1) / OUTC;  // 32 blocks per row
constexpr int NBLK   = B_ROWS * BLKROW;       // 2048 blocks = 8/CU exactly
constexpr int NWAVE  = NT / 64;               // 4 staging rounds

struct Coeffs { float b0, b1, b2, a1, a2; };

__device__ __forceinline__ float rfl(float v) {
    return __int_as_float(__builtin_amdgcn_readfirstlane(__float_as_int(v)));
}

__device__ __forceinline__ Coeffs shelf(float fc, float gdb, float Q) {
    float A  = powf(10.0f, gdb * (1.0f / 40.0f));
    float w0 = 2.0f * 3.14159265358979323846f * fc / 48000.0f;
    float sw = sinf(w0), cw = cosf(w0);
    float alpha = sw / (2.0f * Q);
    float sqA = sqrtf(A);
    float b0 = A * ((A + 1.0f) - (A - 1.0f) * cw + 2.0f * sqA * alpha);
    float b1 = 2.0f * A * ((A - 1.0f) - (A + 1.0f) * cw);
    float b2 = A * ((A + 1.0f) - (A - 1.0f) * cw - 2.0f * sqA * alpha);
    float a0 = (A + 1.0f) + (A - 1.0f) * cw + 2.0f * sqA * alpha;
    float a1 = -2.0f * ((A - 1.0f) + (A + 1.0f) * cw);
    float a2 = (A + 1.0f) + (A - 1.0f) * cw - 2.0f * sqA * alpha;
    float rr = 1.0f / a0;
    Coeffs c;
    c.b0 = rfl(b0 * rr); c.b1 = rfl(b1 * rr); c.b2 = rfl(b2 * rr);
    c.a1 = rfl(a1 * rr); c.a2 = rfl(a2 * rr);
    return c;
}

// DF2T biquad step, op-for-op as reference:
//   y = b0*x + z1; z1' = b1*x - a1*y + z2; z2' = b2*x - a2*y
__device__ __forceinline__ float bq(float xn, const Coeffs& c, float& z1, float& z2) {
    float y = fmaf(c.b0, xn, z1);
    z1 = fmaf(-c.a1, y, fmaf(c.b1, xn, z2));
    z2 = fmaf(c.b2, xn, -(c.a2 * y));
    return y;
}

__device__ __forceinline__ float step6(float s[6], float x,
                                       const Coeffs& c1, const Coeffs& c2, const Coeffs& c3) {
    float y1 = bq(x,  c1, s[0], s[1]);
    float y2 = bq(y1, c2, s[2], s[3]);
    float y3 = bq(y2, c3, s[4], s[5]);
    return y3;
}

// y0 + cn[n].t6 (cn rows stride-8; broadcast LDS reads, const offsets)
__device__ __forceinline__ float corr(float y0, const float* cnp, const float t6[6]) {
    float4 ca = *(const float4*)(cnp);
    float2 cb = *(const float2*)(cnp + 4);
    float acc = fmaf(ca.x, t6[0], y0);
    acc = fmaf(ca.y, t6[1], acc);
    acc = fmaf(ca.z, t6[2], acc);
    acc = fmaf(ca.w, t6[3], acc);
    acc = fmaf(cb.x, t6[4], acc);
    acc = fmaf(cb.y, t6[5], acc);
    return acc;
}

__global__ __launch_bounds__(256, 8) void k_fused(
    const float* __restrict__ x,
    const float* __restrict__ p_lg, const float* __restrict__ p_mg,
    const float* __restrict__ p_mf, const float* __restrict__ p_mq,
    const float* __restrict__ p_hg,
    float* __restrict__ out)
{
    // smem: first NT*7=1792 floats double as the per-thread d store (dl),
    // then (after the pre-combine barrier) the whole 16KB is store staging.
    __shared__ __align__(16) float smem[4096];
    __shared__ float M[36];                      // A^64 workspace
    __shared__ __align__(16) float cn[64 * 8];   // C*A^n rows, stride 8

    const int t = threadIdx.x;
    const int r = blockIdx.x / BLKROW;
    const int b = blockIdx.x - r * BLKROW;
    const int c = b * OUTC + t - HISTC;          // this thread's chunk index
    const bool active = (c >= 0) && (c < KCH);

    Coeffs c1 = shelf(120.0f,  *p_lg, 0.707f);
    Coeffs c2 = shelf(*p_mf,   *p_mg, *p_mq);
    Coeffs c3 = shelf(4000.0f, *p_hg, 0.707f);

    // ---- load chunk into registers ----
    float4 xv[16];
    {
        int cc = c < 0 ? 0 : c;
        const float4* lp = (const float4*)(x + (long long)r * T_LEN + (long long)cc * CHUNK);
        if (active) {
            #pragma unroll
            for (int q = 0; q < 16; ++q) xv[q] = lp[q];
        } else {
            #pragma unroll
            for (int q = 0; q < 16; ++q) xv[q] = make_float4(0.f, 0.f, 0.f, 0.f);
        }
    }

    // ---- pass 1: zero-state response, outputs written in place (y0) ----
    float s[6] = {0.f, 0.f, 0.f, 0.f, 0.f, 0.f};
    #pragma unroll
    for (int q = 0; q < 16; ++q) {
        float4 v = xv[q];
        v.x = step6(s, v.x, c1, c2, c3);
        v.y = step6(s, v.y, c1, c2, c3);
        v.z = step6(s, v.z, c1, c2, c3);
        v.w = step6(s, v.w, c1, c2, c3);
        xv[q] = v;
    }
    #pragma unroll
    for (int i = 0; i < 6; ++i) smem[t * 7 + i] = s[i];

    // ---- A^64 via 6 LDS squarings (threads 0..35 work) ----
    if (t < 6) {
        float e[6] = {0.f, 0.f, 0.f, 0.f, 0.f, 0.f};
        e[t] = 1.0f;
        step6(e, 0.0f, c1, c2, c3);              // column t of A
        #pragma unroll
        for (int i = 0; i < 6; ++i) M[i * 6 + t] = e[i];
    }
    __syncthreads();                              // covers dl + M writes
    for (int it = 0; it < LOG2C; ++it) {
        float acc = 0.f;
        if (t < 36) {
            int i = t / 6, j = t - 6 * (t / 6);
            #pragma unroll
            for (int q = 0; q < 6; ++q) acc = fmaf(M[i * 6 + q], M[q * 6 + j], acc);
        }
        __syncthreads();
        if (t < 36) M[t] = acc;
        __syncthreads();
    }
    float a[36];
    #pragma unroll
    for (int i = 0; i < 36; ++i) a[i] = rfl(M[i]);   // wave-uniform -> SGPR

    // ---- cn table: wave 1 lanes 0..5 simulate homogeneous responses ----
    // Column j of the 64x6 matrix C*A^n: start e_j, 64 zero-input steps,
    // record the cascade output each step. Overlaps other waves' Horner.
    if ((t >> 6) == 1 && (t & 63) < 6) {
        const int j = t & 63;
        float e[6];
        #pragma unroll
        for (int i = 0; i < 6; ++i) e[i] = (i == j) ? 1.0f : 0.0f;
        for (int n = 0; n < 64; ++n) {
            cn[n * 8 + j] = step6(e, 0.0f, c1, c2, c3);
        }
    }

    // ---- truncated Horner scan over predecessors (oldest -> newest) ----
    float t6[6] = {0.f, 0.f, 0.f, 0.f, 0.f, 0.f};
    int m0 = t - MTERM; if (m0 < 0) m0 = 0;
    for (int m = m0; m < t; ++m) {
        float dm[6];
        #pragma unroll
        for (int i = 0; i < 6; ++i) dm[i] = smem[m * 7 + i];
        float nt6[6];
        #pragma unroll
        for (int i = 0; i < 6; ++i) {
            float acc = dm[i];
            #pragma unroll
            for (int j = 0; j < 6; ++j) acc = fmaf(a[i * 6 + j], t6[j], acc);
            nt6[i] = acc;
        }
        #pragma unroll
        for (int i = 0; i < 6; ++i) t6[i] = nt6[i];
    }

    __syncthreads();   // cn ready; all dl reads done (smem reusable)

    // ---- combine: y[n] = y0[n] + cn[n].t6  (6 fma + 2 LDS bcast/sample) ----
    #pragma unroll
    for (int q = 0; q < 16; ++q) {
        float4 v = xv[q];
        v.x = corr(v.x, cn + (4 * q + 0) * 8, t6);
        v.y = corr(v.y, cn + (4 * q + 1) * 8, t6);
        v.z = corr(v.z, cn + (4 * q + 2) * 8, t6);
        v.w = corr(v.w, cn + (4 * q + 3) * 8, t6);
        xv[q] = v;
    }

    // ---- wave-contiguous stores via LDS transpose staging (R5 path) ----
    float4* sv = (float4*)smem;
    const int slot = t & 63;                      // lane within wave
    const int wv   = t >> 6;                      // wave id
    float4* op = (float4*)(out + (long long)r * T_LEN);
    for (int rr = 0; rr < NWAVE; ++rr) {
        if (wv == rr) {
            #pragma unroll
            for (int q = 0; q < 16; ++q) {
                int byte = (slot * 256 + q * 16) ^ ((slot & 7) << 4);
                sv[byte >> 4] = xv[q];
            }
        }
        __syncthreads();                          // stage visible to block
        const int chunkBase = b * OUTC + 64 * rr - HISTC;  // chunk of slot 0
        #pragma unroll
        for (int j = 0; j < 4; ++j) {
            int f  = 256 * j + t;                 // float4 index in 16KB region
            int aa = f >> 4;                      // source slot (0..63)
            int qq = f & 15;                      // float4 within chunk
            int tr = 64 * rr + aa;                // owning thread index
            int cc = chunkBase + aa;              // destination chunk
            if (tr >= HISTC && cc < KCH) {
                int byte = (aa * 256 + qq * 16) ^ ((aa & 7) << 4);
                op[(long long)cc * 16 + qq] = sv[byte >> 4];
            }
        }
        __syncthreads();                          // stage reusable next round
    }
}

extern "C" void kernel_launch(void* const* d_in, const int* in_sizes, int n_in,
                              void* d_out, int out_size, void* d_ws, size_t ws_size,
                              hipStream_t stream) {
    const float* x  = (const float*)d_in[0];
    const float* lg = (const float*)d_in[1];
    const float* mg = (const float*)d_in[2];
    const float* mf = (const float*)d_in[3];
    const float* mq = (const float*)d_in[4];
    const float* hg = (const float*)d_in[5];
    float* out = (float*)d_out;

    hipLaunchKernelGGL(k_fused, dim3(NBLK), dim3(NT), 0, stream,
                       x, lg, mg, mf, mq, hg, out);
}

// Round 4
// 232.577 us; speedup vs baseline: 1.3112x; 1.3112x over previous
//
#include <hip/hip_runtime.h>
#include <math.h>

// ToneStack: 3 cascaded shelf biquads over x[64, 480000] fp32.
//
// R8 = R5 memory structure + R7 algorithmic win, minus R7's two regressions:
//   - R7's __launch_bounds__(256,8) capped regs at 64/wave -> xv[16] (64
//     regs) spilled to SCRATCH (VGPR_Count 32, hbm_bytes 2.4x, 171us).
//     Reverted to R5's proven (256,4) (cap 128; R5 compiled clean).
//   - R7's cn table was a 64-step SERIAL step6 chain on 6 lanes (~3.8k
//     cycles) gating a block barrier. Now: the 6 squarings save their
//     intermediate powers A^(2^k) (864B LDS) + output row C (captured
//     free while building A's columns); lanes 0..63 build cn[n] = C *
//     prod A^(2^k * bit_k(n)) as <=6 row-x-matrix products (~216 fma,
//     fully lane-parallel).
//   Kept from R7: superposition combine (pass1 writes zero-state outputs
//   y0 in place; final y[n] = y0[n] + cn[n].t6, 6 fma + broadcast LDS
//   reads vs 15 VALU of a re-run) and the 2048-block grid (HISTC=MTERM=21,
//   horizon 1344 samples, truncation err ~1e-4 << 0.03125 floor; 32
//   blocks/row -> exactly 2 cohorts at 4 blocks/CU).
//   Store path unchanged from R5 (wave-contiguous 1KB stores via LDS
//   transpose staging, the 137->92us fix).

constexpr int T_LEN  = 480000;
constexpr int B_ROWS = 64;
constexpr int CHUNK  = 64;
constexpr int LOG2C  = 6;                     // A^64 = 6 squarings
constexpr int KCH    = T_LEN / CHUNK;         // 7500 chunks per row
constexpr int NT     = 256;                   // threads per block
constexpr int HISTC  = 21;                    // history chunks (1344 samples)
constexpr int MTERM  = 21;                    // Horner terms (= horizon)
constexpr int OUTC   = NT - HISTC;            // 235 output chunks per block
constexpr int BLKROW = (KCH + OUTC - 1) / OUTC;  // 32 blocks per row
constexpr int NBLK   = B_ROWS * BLKROW;       // 2048 blocks
constexpr int NWAVE  = NT / 64;               // 4 staging rounds

struct Coeffs { float b0, b1, b2, a1, a2; };

__device__ __forceinline__ float rfl(float v) {
    return __int_as_float(__builtin_amdgcn_readfirstlane(__float_as_int(v)));
}

__device__ __forceinline__ Coeffs shelf(float fc, float gdb, float Q) {
    float A  = powf(10.0f, gdb * (1.0f / 40.0f));
    float w0 = 2.0f * 3.14159265358979323846f * fc / 48000.0f;
    float sw = sinf(w0), cw = cosf(w0);
    float alpha = sw / (2.0f * Q);
    float sqA = sqrtf(A);
    float b0 = A * ((A + 1.0f) - (A - 1.0f) * cw + 2.0f * sqA * alpha);
    float b1 = 2.0f * A * ((A - 1.0f) - (A + 1.0f) * cw);
    float b2 = A * ((A + 1.0f) - (A - 1.0f) * cw - 2.0f * sqA * alpha);
    float a0 = (A + 1.0f) + (A - 1.0f) * cw + 2.0f * sqA * alpha;
    float a1 = -2.0f * ((A - 1.0f) + (A + 1.0f) * cw);
    float a2 = (A + 1.0f) + (A - 1.0f) * cw - 2.0f * sqA * alpha;
    float rr = 1.0f / a0;
    Coeffs c;
    c.b0 = rfl(b0 * rr); c.b1 = rfl(b1 * rr); c.b2 = rfl(b2 * rr);
    c.a1 = rfl(a1 * rr); c.a2 = rfl(a2 * rr);
    return c;
}

// DF2T biquad step, op-for-op as reference:
//   y = b0*x + z1; z1' = b1*x - a1*y + z2; z2' = b2*x - a2*y
__device__ __forceinline__ float bq(float xn, const Coeffs& c, float& z1, float& z2) {
    float y = fmaf(c.b0, xn, z1);
    z1 = fmaf(-c.a1, y, fmaf(c.b1, xn, z2));
    z2 = fmaf(c.b2, xn, -(c.a2 * y));
    return y;
}

__device__ __forceinline__ float step6(float s[6], float x,
                                       const Coeffs& c1, const Coeffs& c2, const Coeffs& c3) {
    float y1 = bq(x,  c1, s[0], s[1]);
    float y2 = bq(y1, c2, s[2], s[3]);
    float y3 = bq(y2, c3, s[4], s[5]);
    return y3;
}

// y0 + cn[n].t6 (cn rows stride-8; broadcast LDS reads, const offsets)
__device__ __forceinline__ float corr(float y0, const float* cnp, const float t6[6]) {
    float4 ca = *(const float4*)(cnp);
    float2 cb = *(const float2*)(cnp + 4);
    float acc = fmaf(ca.x, t6[0], y0);
    acc = fmaf(ca.y, t6[1], acc);
    acc = fmaf(ca.z, t6[2], acc);
    acc = fmaf(ca.w, t6[3], acc);
    acc = fmaf(cb.x, t6[4], acc);
    acc = fmaf(cb.y, t6[5], acc);
    return acc;
}

__global__ __launch_bounds__(256, 4) void k_fused(
    const float* __restrict__ x,
    const float* __restrict__ p_lg, const float* __restrict__ p_mg,
    const float* __restrict__ p_mf, const float* __restrict__ p_mq,
    const float* __restrict__ p_hg,
    float* __restrict__ out)
{
    // smem: first NT*7=1792 floats double as the per-thread d store (dl),
    // then (after the pre-combine barrier) the whole 16KB is store staging.
    __shared__ __align__(16) float smem[4096];
    __shared__ float M[36];                      // squaring workspace -> A^64
    __shared__ float Pw[LOG2C * 36];             // A^1,A^2,A^4,A^8,A^16,A^32
    __shared__ float Crow[8];                    // output row C of the cascade
    __shared__ __align__(16) float cn[64 * 8];   // C*A^n rows, stride 8

    const int t = threadIdx.x;
    const int r = blockIdx.x / BLKROW;
    const int b = blockIdx.x - r * BLKROW;
    const int c = b * OUTC + t - HISTC;          // this thread's chunk index
    const bool active = (c >= 0) && (c < KCH);

    Coeffs c1 = shelf(120.0f,  *p_lg, 0.707f);
    Coeffs c2 = shelf(*p_mf,   *p_mg, *p_mq);
    Coeffs c3 = shelf(4000.0f, *p_hg, 0.707f);

    // ---- load chunk into registers ----
    float4 xv[16];
    {
        int cc = c < 0 ? 0 : c;
        const float4* lp = (const float4*)(x + (long long)r * T_LEN + (long long)cc * CHUNK);
        if (active) {
            #pragma unroll
            for (int q = 0; q < 16; ++q) xv[q] = lp[q];
        } else {
            #pragma unroll
            for (int q = 0; q < 16; ++q) xv[q] = make_float4(0.f, 0.f, 0.f, 0.f);
        }
    }

    // ---- pass 1: zero-state response, outputs written in place (y0) ----
    float s[6] = {0.f, 0.f, 0.f, 0.f, 0.f, 0.f};
    #pragma unroll
    for (int q = 0; q < 16; ++q) {
        float4 v = xv[q];
        v.x = step6(s, v.x, c1, c2, c3);
        v.y = step6(s, v.y, c1, c2, c3);
        v.z = step6(s, v.z, c1, c2, c3);
        v.w = step6(s, v.w, c1, c2, c3);
        xv[q] = v;
    }
    #pragma unroll
    for (int i = 0; i < 6; ++i) smem[t * 7 + i] = s[i];

    // ---- A columns + output row C (threads 0..5) ----
    if (t < 6) {
        float e[6] = {0.f, 0.f, 0.f, 0.f, 0.f, 0.f};
        e[t] = 1.0f;
        float y = step6(e, 0.0f, c1, c2, c3);    // one zero-input step from e_t
        #pragma unroll
        for (int i = 0; i < 6; ++i) M[i * 6 + t] = e[i];   // A[:,t]
        Crow[t] = y;                                        // C[t]
    }
    __syncthreads();                              // covers dl + M + Crow

    // ---- A^64 via 6 squarings; save each power A^(2^it) first ----
    for (int it = 0; it < LOG2C; ++it) {
        float acc = 0.f;
        if (t < 36) {
            Pw[it * 36 + t] = M[t];               // snapshot A^(2^it)
            int i = t / 6, j = t - 6 * (t / 6);
            #pragma unroll
            for (int q = 0; q < 6; ++q) acc = fmaf(M[i * 6 + q], M[q * 6 + j], acc);
        }
        __syncthreads();
        if (t < 36) M[t] = acc;
        __syncthreads();
    }
    float a[36];
    #pragma unroll
    for (int i = 0; i < 36; ++i) a[i] = rfl(M[i]);   // A^64, wave-uniform -> SGPR

    // ---- cn rows, lane-parallel: cn[n] = C * prod_k A^(2^k * bit_k(n)) ----
    // Powers of the same A commute, so any multiplication order is valid.
    if (t < 64) {
        float row[6];
        #pragma unroll
        for (int j = 0; j < 6; ++j) row[j] = Crow[j];
        for (int k = 0; k < LOG2C; ++k) {
            if ((t >> k) & 1) {
                const float* P = Pw + k * 36;
                float nr[6];
                #pragma unroll
                for (int j = 0; j < 6; ++j) {
                    float acc = 0.f;
                    #pragma unroll
                    for (int q = 0; q < 6; ++q) acc = fmaf(row[q], P[q * 6 + j], acc);
                    nr[j] = acc;
                }
                #pragma unroll
                for (int j = 0; j < 6; ++j) row[j] = nr[j];
            }
        }
        #pragma unroll
        for (int j = 0; j < 6; ++j) cn[t * 8 + j] = row[j];
    }

    // ---- truncated Horner scan over predecessors (oldest -> newest) ----
    float t6[6] = {0.f, 0.f, 0.f, 0.f, 0.f, 0.f};
    int m0 = t - MTERM; if (m0 < 0) m0 = 0;
    for (int m = m0; m < t; ++m) {
        float dm[6];
        #pragma unroll
        for (int i = 0; i < 6; ++i) dm[i] = smem[m * 7 + i];
        float nt6[6];
        #pragma unroll
        for (int i = 0; i < 6; ++i) {
            float acc = dm[i];
            #pragma unroll
            for (int j = 0; j < 6; ++j) acc = fmaf(a[i * 6 + j], t6[j], acc);
            nt6[i] = acc;
        }
        #pragma unroll
        for (int i = 0; i < 6; ++i) t6[i] = nt6[i];
    }

    __syncthreads();   // cn ready; all dl reads done (smem reusable)

    // ---- combine: y[n] = y0[n] + cn[n].t6  (6 fma + 2 LDS bcast/sample) ----
    #pragma unroll
    for (int q = 0; q < 16; ++q) {
        float4 v = xv[q];
        v.x = corr(v.x, cn + (4 * q + 0) * 8, t6);
        v.y = corr(v.y, cn + (4 * q + 1) * 8, t6);
        v.z = corr(v.z, cn + (4 * q + 2) * 8, t6);
        v.w = corr(v.w, cn + (4 * q + 3) * 8, t6);
        xv[q] = v;
    }

    // ---- wave-contiguous stores via LDS transpose staging (R5 path) ----
    float4* sv = (float4*)smem;
    const int slot = t & 63;                      // lane within wave
    const int wv   = t >> 6;                      // wave id
    float4* op = (float4*)(out + (long long)r * T_LEN);
    for (int rr = 0; rr < NWAVE; ++rr) {
        if (wv == rr) {
            #pragma unroll
            for (int q = 0; q < 16; ++q) {
                int byte = (slot * 256 + q * 16) ^ ((slot & 7) << 4);
                sv[byte >> 4] = xv[q];
            }
        }
        __syncthreads();                          // stage visible to block
        const int chunkBase = b * OUTC + 64 * rr - HISTC;  // chunk of slot 0
        #pragma unroll
        for (int j = 0; j < 4; ++j) {
            int f  = 256 * j + t;                 // float4 index in 16KB region
            int aa = f >> 4;                      // source slot (0..63)
            int qq = f & 15;                      // float4 within chunk
            int tr = 64 * rr + aa;                // owning thread index
            int cc = chunkBase + aa;              // destination chunk
            if (tr >= HISTC && cc < KCH) {
                int byte = (aa * 256 + qq * 16) ^ ((aa & 7) << 4);
                op[(long long)cc * 16 + qq] = sv[byte >> 4];
            }
        }
        __syncthreads();                          // stage reusable next round
    }
}

extern "C" void kernel_launch(void* const* d_in, const int* in_sizes, int n_in,
                              void* d_out, int out_size, void* d_ws, size_t ws_size,
                              hipStream_t stream) {
    const float* x  = (const float*)d_in[0];
    const float* lg = (const float*)d_in[1];
    const float* mg = (const float*)d_in[2];
    const float* mf = (const float*)d_in[3];
    const float* mq = (const float*)d_in[4];
    const float* hg = (const float*)d_in[5];
    float* out = (float*)d_out;

    hipLaunchKernelGGL(k_fused, dim3(NBLK), dim3(NT), 0, stream,
                       x, lg, mg, mf, mq, hg, out);
}